// Round 13
// baseline (814.850 us; speedup 1.0000x reference)
//
#include <hip/hip_runtime.h>
#include <hip/hip_cooperative_groups.h>
#include <math.h>

namespace cg = cooperative_groups;

#define Bq 16
#define Sq 1024
#define Dq 128
#define Hq 8
#define DHq 16
#define DFFq 512
#define Lq 3
#define NCLS 6
#define NROWS (Bq * Sq)       // 16384
#define NX ((size_t)NROWS * Dq)   // 2,097,152 floats
#define PREP_N 2637824

typedef __attribute__((ext_vector_type(8))) short    bf16x8;
typedef __attribute__((ext_vector_type(4))) float    f32x4;
typedef __attribute__((ext_vector_type(4))) _Float16 f16x4;
typedef __attribute__((ext_vector_type(8))) _Float16 f16x8;

__device__ inline ushort f32_to_bf16(float f) {
    union { float f; unsigned u; } v; v.f = f;
    unsigned r = v.u + 0x7fffu + ((v.u >> 16) & 1u);
    return (ushort)(r >> 16);
}

// ---------------------------------------------------------------------------
// prep element: cast+transpose weights to bf16 Wt[n][k]; cast x to bf16.
// Wq PRE-SCALED by 0.25.
// ---------------------------------------------------------------------------
__device__ __forceinline__ void prep_one(
    int gid,
    const float* __restrict__ Wqp, const float* __restrict__ Wkp,
    const float* __restrict__ Wvp, const float* __restrict__ W1p,
    const float* __restrict__ W2p, const float* __restrict__ xp,
    ushort* __restrict__ wbf, ushort* __restrict__ xbf)
{
    if (gid < 147456) {
        const int w   = gid / 49152;
        const int rem = gid - w * 49152;
        const int l   = rem >> 14;
        const int idx = rem & 16383;
        const int k   = idx >> 7;
        const int n   = idx & 127;
        const float* src = (w == 0) ? Wqp : (w == 1) ? Wkp : Wvp;
        const float scl = (w == 0) ? 0.25f : 1.0f;
        wbf[(size_t)(w * 3 + l) * 16384 + n * 128 + k] =
            f32_to_bf16(src[(size_t)l * 16384 + k * 128 + n] * scl);
    } else if (gid < 344064) {
        const int g   = gid - 147456;
        const int l   = g >> 16;
        const int idx = g & 65535;
        const int k   = idx >> 9;
        const int n   = idx & 511;
        wbf[147456 + (size_t)l * 65536 + n * 128 + k] =
            f32_to_bf16(W1p[(size_t)l * 65536 + k * 512 + n]);
    } else if (gid < 540672) {
        const int g   = gid - 344064;
        const int l   = g >> 16;
        const int idx = g & 65535;
        const int k   = idx >> 7;
        const int n   = idx & 127;
        wbf[344064 + (size_t)l * 65536 + n * 512 + k] =
            f32_to_bf16(W2p[(size_t)l * 65536 + k * 128 + n]);
    } else {
        const int g = gid - 540672;
        xbf[g] = f32_to_bf16(xp[g]);
    }
}

// ---------------------------------------------------------------------------
// QKV tile (R12-proven body). smem needs 15360 B.
// sel=0: Q (pre-scaled) -> [b,h,s,dh] f16; 1: K same; 2: V -> [b,h,dh,s] f16
// ---------------------------------------------------------------------------
__device__ __forceinline__ void qkv_tile(
    char* smem, int sel, int row0,
    const ushort* __restrict__ A,
    const ushort* __restrict__ wq, const ushort* __restrict__ wk,
    const ushort* __restrict__ wv,
    const float* __restrict__ bqp, const float* __restrict__ bkp,
    const float* __restrict__ bvp,
    _Float16* __restrict__ qo, _Float16* __restrict__ ko,
    _Float16* __restrict__ vo)
{
    ushort* As = (ushort*)smem;            // 64*40
    ushort* Bs = (ushort*)smem + 2560;     // 128*40

    const ushort* Bt   = (sel == 0) ? wq : (sel == 1) ? wk : wv;
    const float*  bias = (sel == 0) ? bqp : (sel == 1) ? bkp : bvp;
    const float   bscl = (sel == 0) ? 0.25f : 1.0f;

    const int tid  = threadIdx.x;
    const int wave = tid >> 6;
    const int lane = tid & 63;
    const int quad = lane >> 4;
    const int m16  = lane & 15;
    const int wm   = wave >> 1;
    const int wn   = wave & 1;
    const int sar  = tid >> 2;
    const int sac  = (tid & 3) * 8;
    const int r1   = tid >> 2, r2 = r1 + 64;

    f32x4 acc[2][4];
    #pragma unroll
    for (int i = 0; i < 2; ++i)
        #pragma unroll
        for (int j = 0; j < 4; ++j) acc[i][j] = (f32x4)0.f;

    for (int k0 = 0; k0 < 128; k0 += 32) {
        bf16x8 av  = *(const bf16x8*)(A + (size_t)(row0 + sar) * 128 + k0 + sac);
        bf16x8 bv1 = *(const bf16x8*)(Bt + (size_t)r1 * 128 + k0 + sac);
        bf16x8 bv2 = *(const bf16x8*)(Bt + (size_t)r2 * 128 + k0 + sac);

        __syncthreads();
        *(bf16x8*)&As[sar * 40 + sac] = av;
        *(bf16x8*)&Bs[r1 * 40 + sac]  = bv1;
        *(bf16x8*)&Bs[r2 * 40 + sac]  = bv2;
        __syncthreads();

        bf16x8 af[2], bf[4];
        #pragma unroll
        for (int i = 0; i < 2; ++i)
            af[i] = *(const bf16x8*)&As[(32 * wm + 16 * i + m16) * 40 + quad * 8];
        #pragma unroll
        for (int j = 0; j < 4; ++j)
            bf[j] = *(const bf16x8*)&Bs[(64 * wn + 16 * j + m16) * 40 + quad * 8];
        #pragma unroll
        for (int i = 0; i < 2; ++i)
            #pragma unroll
            for (int j = 0; j < 4; ++j)
                acc[i][j] = __builtin_amdgcn_mfma_f32_16x16x32_bf16(af[i], bf[j], acc[i][j], 0, 0, 0);
    }

    #pragma unroll
    for (int i = 0; i < 2; ++i) {
        #pragma unroll
        for (int j = 0; j < 4; ++j) {
            const int col = 64 * wn + 16 * j + m16;
            const float bb = bias[col] * bscl;
            const int hh = col >> 4, dh = col & 15;
            #pragma unroll
            for (int r = 0; r < 4; ++r) {
                float val = fmaxf(acc[i][j][r] + bb, 0.f);
                const int gr = row0 + 32 * wm + 16 * i + quad * 4 + r;
                const int b = gr >> 10, s = gr & 1023;
                if (sel == 2) {
                    vo[(((size_t)b * Hq + hh) * DHq + dh) * Sq + s] = (_Float16)val;
                } else {
                    _Float16* outp = (sel == 0) ? qo : ko;
                    outp[(((size_t)b * Hq + hh) * Sq + s) * DHq + dh] = (_Float16)val;
                }
            }
        }
    }
}

// ---------------------------------------------------------------------------
// Attention unit (R12-proven body). smem needs 18688 B.
// ---------------------------------------------------------------------------
__device__ __forceinline__ void attn_unit(
    char* smem, int bh, int qc,
    const _Float16* __restrict__ q, const _Float16* __restrict__ k,
    const _Float16* __restrict__ vt, float* __restrict__ o)
{
    _Float16* Ks = (_Float16*)smem;             // 256*20
    _Float16* Vs = (_Float16*)(smem + 10240);   // 16*264

    const int b    = bh >> 3;
    const int h    = bh & 7;
    const int tid  = threadIdx.x;
    const int wave = tid >> 6;
    const int lane = tid & 63;
    const int quad = lane >> 4;
    const int m16  = lane & 15;
    const int q0   = qc * 128 + wave * 32;

    const f16x4 qf0 = *(const f16x4*)(q + (((size_t)bh * Sq) + q0 + m16) * DHq + quad * 4);
    const f16x4 qf1 = *(const f16x4*)(q + (((size_t)bh * Sq) + q0 + 16 + m16) * DHq + quad * 4);

    const _Float16* kg  = k  + (size_t)bh * Sq * DHq;
    const _Float16* vtg = vt + (size_t)bh * DHq * Sq;

    f32x4 oacc0 = (f32x4)0.f, oacc1 = (f32x4)0.f;
    float lacc0 = 0.f, lacc1 = 0.f;

    const int krow = tid;
    const int vrow = tid >> 4;
    const int vcol = (tid & 15) * 16;

    for (int kb = 0; kb < 4; ++kb) {
        f16x8 ka  = *(const f16x8*)(kg + ((size_t)kb * 256 + krow) * DHq);
        f16x8 kb8 = *(const f16x8*)(kg + ((size_t)kb * 256 + krow) * DHq + 8);
        f16x8 va  = *(const f16x8*)(vtg + (size_t)vrow * Sq + kb * 256 + vcol);
        f16x8 vb  = *(const f16x8*)(vtg + (size_t)vrow * Sq + kb * 256 + vcol + 8);
        __syncthreads();
        *(f16x8*)&Ks[krow * 20 + 0] = ka;
        *(f16x8*)&Ks[krow * 20 + 8] = kb8;
        *(f16x8*)&Vs[vrow * 264 + vcol + 0] = va;
        *(f16x8*)&Vs[vrow * 264 + vcol + 8] = vb;
        __syncthreads();

        #pragma unroll 4
        for (int kt = 0; kt < 16; ++kt) {
            const f16x4 kf = *(const f16x4*)&Ks[(kt * 16 + m16) * 20 + quad * 4];
            const f16x4 vf = *(const f16x4*)&Vs[m16 * 264 + kt * 16 + quad * 4];

            f32x4 st0 = __builtin_amdgcn_mfma_f32_16x16x16f16(kf, qf0, (f32x4)0.f, 0, 0, 0);
            f32x4 st1 = __builtin_amdgcn_mfma_f32_16x16x16f16(kf, qf1, (f32x4)0.f, 0, 0, 0);

            float p00 = __expf(st0[0]);
            float p01 = __expf(st0[1]);
            float p02 = __expf(st0[2]);
            float p03 = __expf(st0[3]);
            float p10 = __expf(st1[0]);
            float p11 = __expf(st1[1]);
            float p12 = __expf(st1[2]);
            float p13 = __expf(st1[3]);
            lacc0 += (p00 + p01) + (p02 + p03);
            lacc1 += (p10 + p11) + (p12 + p13);

            f16x4 pf0, pf1;
            pf0[0] = (_Float16)p00; pf0[1] = (_Float16)p01;
            pf0[2] = (_Float16)p02; pf0[3] = (_Float16)p03;
            pf1[0] = (_Float16)p10; pf1[1] = (_Float16)p11;
            pf1[2] = (_Float16)p12; pf1[3] = (_Float16)p13;

            oacc0 = __builtin_amdgcn_mfma_f32_16x16x16f16(pf0, vf, oacc0, 0, 0, 0);
            oacc1 = __builtin_amdgcn_mfma_f32_16x16x16f16(pf1, vf, oacc1, 0, 0, 0);
        }
    }

    lacc0 += __shfl_xor(lacc0, 16, 64);
    lacc0 += __shfl_xor(lacc0, 32, 64);
    lacc1 += __shfl_xor(lacc1, 16, 64);
    lacc1 += __shfl_xor(lacc1, 32, 64);

    #pragma unroll
    for (int r = 0; r < 4; ++r) {
        const float ls0 = __shfl(lacc0, quad * 4 + r, 64);
        const float ls1 = __shfl(lacc1, quad * 4 + r, 64);
        o[((size_t)b * Sq + q0 + quad * 4 + r) * Dq + h * DHq + m16]      = oacc0[r] / ls0;
        o[((size_t)b * Sq + q0 + 16 + quad * 4 + r) * Dq + h * DHq + m16] = oacc1[r] / ls1;
    }
}

// ---------------------------------------------------------------------------
// Fused FFN unit (R12-proven body, 64-K staging). smem needs 69120 B.
// ---------------------------------------------------------------------------
__device__ __forceinline__ void ffn_unit(
    char* smem, int row0,
    const float* __restrict__ o, const float* __restrict__ resid,
    const float* __restrict__ g1, const float* __restrict__ beta1,
    const ushort* __restrict__ W1t, const float* __restrict__ bias1,
    const ushort* __restrict__ W2t, const float* __restrict__ bias2,
    const float* __restrict__ g2, const float* __restrict__ beta2,
    float* __restrict__ xb, ushort* __restrict__ xbbf,
    const float* __restrict__ Wout, const float* __restrict__ bout,
    float* __restrict__ out, int last)
{
    ushort*    Af   = (ushort*)smem;                 // 32x136 bf16
    ushort*    Hs   = (ushort*)(smem + 8704);        // 32x520 bf16
    ushort*    Bs   = (ushort*)(smem + 41984);       // 128x72 staging
    float*     wo_s = (float*)(smem + 41984);        // overlays Bs in phase D
    _Float16*  vals = (_Float16*)(smem + 60416);     // 32x132 f16
    float*     mus  = (float*)(smem + 68864);
    float*     rsds = (float*)(smem + 68992);

    const int tid  = threadIdx.x;
    const int wave = tid >> 6;
    const int lane = tid & 63;
    const int quad = lane >> 4;
    const int m16  = lane & 15;
    const int wm   = wave >> 1;
    const int wn   = wave & 1;
    const int sac  = (tid & 3) * 8;
    const int r1   = tid >> 2, r2 = r1 + 64;

    // ---- Phase A: LN1 ----
    #pragma unroll 2
    for (int it = 0; it < 8; ++it) {
        const int rr = wave * 8 + it;
        const size_t base = (size_t)(row0 + rr) * Dq;
        float v0 = o[base + lane]      + resid[base + lane];
        float v1 = o[base + 64 + lane] + resid[base + 64 + lane];

        float s = v0 + v1;
        #pragma unroll
        for (int off = 32; off > 0; off >>= 1) s += __shfl_xor(s, off, 64);
        const float mu = s * (1.f / 128.f);
        const float d0 = v0 - mu, d1 = v1 - mu;
        float vs = d0 * d0 + d1 * d1;
        #pragma unroll
        for (int off = 32; off > 0; off >>= 1) vs += __shfl_xor(vs, off, 64);
        const float rstd = rsqrtf(vs * (1.f / 128.f) + 1e-8f);

        const float rv0 = g1[lane]      * d0 * rstd + beta1[lane];
        const float rv1 = g1[lane + 64] * d1 * rstd + beta1[lane + 64];
        Af[rr * 136 + lane]        = f32_to_bf16(rv0);
        Af[rr * 136 + 64 + lane]   = f32_to_bf16(rv1);
        vals[rr * 132 + lane]      = (_Float16)rv0;
        vals[rr * 132 + 64 + lane] = (_Float16)rv1;
    }

    // ---- Phase B: FFN1, h -> Hs ----
    f32x4 acc[4];
    #pragma unroll
    for (int j = 0; j < 4; ++j) acc[j] = (f32x4)0.f;

    for (int idx = 0; idx < 8; ++idx) {
        const int cc = idx >> 1;
        const int k0 = (idx & 1) * 64;

        bf16x8 w11 = *(const bf16x8*)(W1t + (size_t)(cc * 128 + r1) * 128 + k0 + sac);
        bf16x8 w12 = *(const bf16x8*)(W1t + (size_t)(cc * 128 + r1) * 128 + k0 + 32 + sac);
        bf16x8 w21 = *(const bf16x8*)(W1t + (size_t)(cc * 128 + r2) * 128 + k0 + sac);
        bf16x8 w22 = *(const bf16x8*)(W1t + (size_t)(cc * 128 + r2) * 128 + k0 + 32 + sac);

        __syncthreads();
        *(bf16x8*)&Bs[r1 * 72 + sac]      = w11;
        *(bf16x8*)&Bs[r1 * 72 + 32 + sac] = w12;
        *(bf16x8*)&Bs[r2 * 72 + sac]      = w21;
        *(bf16x8*)&Bs[r2 * 72 + 32 + sac] = w22;
        __syncthreads();

        #pragma unroll
        for (int hh = 0; hh < 2; ++hh) {
            const int kk = k0 + hh * 32;
            const bf16x8 af = *(const bf16x8*)&Af[(16 * wm + m16) * 136 + kk + quad * 8];
            bf16x8 bf[4];
            #pragma unroll
            for (int j = 0; j < 4; ++j)
                bf[j] = *(const bf16x8*)&Bs[(64 * wn + 16 * j + m16) * 72 + hh * 32 + quad * 8];
            #pragma unroll
            for (int j = 0; j < 4; ++j)
                acc[j] = __builtin_amdgcn_mfma_f32_16x16x32_bf16(af, bf[j], acc[j], 0, 0, 0);
        }

        if (idx & 1) {
            #pragma unroll
            for (int j = 0; j < 4; ++j) {
                const int col = cc * 128 + 64 * wn + 16 * j + m16;
                const float bb = bias1[col];
                #pragma unroll
                for (int r = 0; r < 4; ++r) {
                    const int row = 16 * wm + quad * 4 + r;
                    Hs[row * 520 + col] = f32_to_bf16(fmaxf(acc[j][r] + bb, 0.f));
                }
                acc[j] = (f32x4)0.f;
            }
        }
    }

    // ---- Phase C: FFN2 from resident Hs ----
    f32x4 acc2[4];
    #pragma unroll
    for (int j = 0; j < 4; ++j) acc2[j] = (f32x4)0.f;

    for (int kc = 0; kc < 8; ++kc) {
        const int k0 = kc * 64;

        bf16x8 w11 = *(const bf16x8*)(W2t + (size_t)r1 * DFFq + k0 + sac);
        bf16x8 w12 = *(const bf16x8*)(W2t + (size_t)r1 * DFFq + k0 + 32 + sac);
        bf16x8 w21 = *(const bf16x8*)(W2t + (size_t)r2 * DFFq + k0 + sac);
        bf16x8 w22 = *(const bf16x8*)(W2t + (size_t)r2 * DFFq + k0 + 32 + sac);

        __syncthreads();
        *(bf16x8*)&Bs[r1 * 72 + sac]      = w11;
        *(bf16x8*)&Bs[r1 * 72 + 32 + sac] = w12;
        *(bf16x8*)&Bs[r2 * 72 + sac]      = w21;
        *(bf16x8*)&Bs[r2 * 72 + 32 + sac] = w22;
        __syncthreads();

        #pragma unroll
        for (int hh = 0; hh < 2; ++hh) {
            const int kk = k0 + hh * 32;
            const bf16x8 af = *(const bf16x8*)&Hs[(16 * wm + m16) * 520 + kk + quad * 8];
            bf16x8 bf[4];
            #pragma unroll
            for (int j = 0; j < 4; ++j)
                bf[j] = *(const bf16x8*)&Bs[(64 * wn + 16 * j + m16) * 72 + hh * 32 + quad * 8];
            #pragma unroll
            for (int j = 0; j < 4; ++j)
                acc2[j] = __builtin_amdgcn_mfma_f32_16x16x32_bf16(af, bf[j], acc2[j], 0, 0, 0);
        }
    }

    // ---- Phase D ----
    __syncthreads();

    float vreg[4][4];
    #pragma unroll
    for (int j = 0; j < 4; ++j) {
        const int col = 64 * wn + 16 * j + m16;
        const float bb = bias2[col];
        #pragma unroll
        for (int r = 0; r < 4; ++r) {
            const int row = 16 * wm + quad * 4 + r;
            float v = acc2[j][r] + bb + (float)vals[row * 132 + col];
            vreg[j][r] = v;
            vals[row * 132 + col] = (_Float16)v;
        }
    }
    if (last) {
        #pragma unroll
        for (int i = 0; i < 3; ++i) wo_s[tid + i * 256] = Wout[tid + i * 256];
    }
    __syncthreads();

    if (tid < 32) {
        float s = 0.f, s2 = 0.f;
        #pragma unroll 8
        for (int c = 0; c < Dq; ++c) {
            float x = (float)vals[tid * 132 + c];
            s += x; s2 = fmaf(x, x, s2);
        }
        const float mu  = s * (1.f / 128.f);
        const float var = s2 * (1.f / 128.f) - mu * mu;
        mus[tid]  = mu;
        rsds[tid] = rsqrtf(var + 1e-6f);
    }
    __syncthreads();

    if (!last) {
        #pragma unroll
        for (int j = 0; j < 4; ++j) {
            const int col = 64 * wn + 16 * j + m16;
            #pragma unroll
            for (int r = 0; r < 4; ++r) {
                const int row = 16 * wm + quad * 4 + r;
                const float rn = g2[col] * (vreg[j][r] - mus[row]) * rsds[row] + beta2[col];
                const size_t idx = (size_t)(row0 + row) * Dq + col;
                xb[idx]   = rn;
                xbbf[idx] = f32_to_bf16(rn);
            }
        }
    } else {
        #pragma unroll
        for (int j = 0; j < 4; ++j) {
            const int col = 64 * wn + 16 * j + m16;
            #pragma unroll
            for (int r = 0; r < 4; ++r) {
                const int row = 16 * wm + quad * 4 + r;
                vals[row * 132 + col] =
                    (_Float16)(g2[col] * (vreg[j][r] - mus[row]) * rsds[row] + beta2[col]);
            }
        }
        __syncthreads();
        if (tid < 32 * NCLS) {
            const int row = tid / NCLS;
            const int c   = tid - row * NCLS;
            float a = bout[c];
            #pragma unroll 8
            for (int kk = 0; kk < Dq; ++kk)
                a = fmaf((float)vals[row * 132 + kk], wo_s[kk * NCLS + c], a);
            out[(size_t)(row0 + row) * NCLS + c] = a;
        }
    }
}

// ---------------------------------------------------------------------------
struct MegaArgs {
    const float *x_in, *Wq, *bq, *Wk, *bk, *Wv, *bv;
    const float *ln1_g, *ln1_b, *W1, *b1, *W2, *b2, *ln2_g, *ln2_b, *Wout, *bout;
    float* out;
    ushort* wbf; ushort* xbf0;
    _Float16 *qf16, *kf16, *vt16;
    float* obuf; float* xb; ushort* xbbf;
};

// Cooperative mega-kernel: all 10 dispatches in one launch, phases separated
// by grid.sync(). grid=512 (2 blocks/CU at 69 KB LDS), work per phase matches
// the standalone kernels' concurrency exactly (qkv 768u/2rds, attn 1024u/2rds,
// ffn 512u/1rd).
__global__ __launch_bounds__(256, 2) void mega_kernel(MegaArgs a)
{
    __shared__ __align__(16) char smem[69120];
    cg::grid_group grid = cg::this_grid();
    const int tid = threadIdx.x;

    for (int gid = blockIdx.x * 256 + tid; gid < PREP_N; gid += 512 * 256)
        prep_one(gid, a.Wq, a.Wk, a.Wv, a.W1, a.W2, a.x_in, a.wbf, a.xbf0);
    grid.sync();

    for (int l = 0; l < Lq; ++l) {
        const ushort* wqt = a.wbf + (size_t)(0 * 3 + l) * 16384;
        const ushort* wkt = a.wbf + (size_t)(1 * 3 + l) * 16384;
        const ushort* wvt = a.wbf + (size_t)(2 * 3 + l) * 16384;
        const ushort* w1t = a.wbf + 147456 + (size_t)l * 65536;
        const ushort* w2t = a.wbf + 344064 + (size_t)l * 65536;
        const ushort* xcur_bf = (l == 0) ? a.xbf0 : a.xbbf;
        const float*  resid   = (l == 0) ? a.x_in : a.xb;

        for (int u = blockIdx.x; u < 768; u += 512)
            qkv_tile(smem, u >> 8, (u & 255) * 64, xcur_bf, wqt, wkt, wvt,
                     a.bq + l * Dq, a.bk + l * Dq, a.bv + l * Dq,
                     a.qf16, a.kf16, a.vt16);
        grid.sync();

        for (int u = blockIdx.x; u < 1024; u += 512)
            attn_unit(smem, u >> 3, u & 7, a.qf16, a.kf16, a.vt16, a.obuf);
        grid.sync();

        ffn_unit(smem, blockIdx.x * 32, a.obuf, resid,
                 a.ln1_g + l * Dq, a.ln1_b + l * Dq,
                 w1t, a.b1 + l * DFFq, w2t, a.b2 + l * Dq,
                 a.ln2_g + l * Dq, a.ln2_b + l * Dq,
                 a.xb, a.xbbf, a.Wout, a.bout, a.out, (l == Lq - 1) ? 1 : 0);
        if (l < Lq - 1) grid.sync();
    }
}

// ---------------------------------------------------------------------------
// Fallback standalone kernels (R12-equivalent), sharing the device bodies.
// ---------------------------------------------------------------------------
__global__ __launch_bounds__(256) void prep_kernel_fb(
    const float* Wqp, const float* Wkp, const float* Wvp,
    const float* W1p, const float* W2p, const float* xp,
    ushort* wbf, ushort* xbf)
{
    const int gid = blockIdx.x * 256 + threadIdx.x;
    if (gid < PREP_N)
        prep_one(gid, Wqp, Wkp, Wvp, W1p, W2p, xp, wbf, xbf);
}

__global__ __launch_bounds__(256) void qkv_kernel_fb(
    const ushort* A, const ushort* wq, const ushort* wk, const ushort* wv,
    const float* bqp, const float* bkp, const float* bvp,
    _Float16* qo, _Float16* ko, _Float16* vo)
{
    __shared__ __align__(16) char smem[15360];
    qkv_tile(smem, blockIdx.y, blockIdx.x * 64, A, wq, wk, wv, bqp, bkp, bvp, qo, ko, vo);
}

__global__ __launch_bounds__(256) void attn_kernel_fb(
    const _Float16* q, const _Float16* k, const _Float16* vt, float* o)
{
    __shared__ __align__(16) char smem[18688];
    attn_unit(smem, blockIdx.x, blockIdx.y, q, k, vt, o);
}

__global__ __launch_bounds__(256) void ffn_kernel_fb(
    const float* o, const float* resid,
    const float* g1, const float* beta1,
    const ushort* W1t, const float* bias1,
    const ushort* W2t, const float* bias2,
    const float* g2, const float* beta2,
    float* xb, ushort* xbbf,
    const float* Wout, const float* bout, float* out, int last)
{
    __shared__ __align__(16) char smem[69120];
    ffn_unit(smem, blockIdx.x * 32, o, resid, g1, beta1, W1t, bias1,
             W2t, bias2, g2, beta2, xb, xbbf, Wout, bout, out, last);
}

// ---------------------------------------------------------------------------
extern "C" void kernel_launch(void* const* d_in, const int* in_sizes, int n_in,
                              void* d_out, int out_size, void* d_ws, size_t ws_size,
                              hipStream_t stream)
{
    const float* x_in  = (const float*)d_in[0];
    const float* Wq    = (const float*)d_in[1];
    const float* bq    = (const float*)d_in[2];
    const float* Wk    = (const float*)d_in[3];
    const float* bk    = (const float*)d_in[4];
    const float* Wv    = (const float*)d_in[5];
    const float* bv    = (const float*)d_in[6];
    const float* ln1_g = (const float*)d_in[7];
    const float* ln1_b = (const float*)d_in[8];
    const float* W1    = (const float*)d_in[9];
    const float* b1    = (const float*)d_in[10];
    const float* W2    = (const float*)d_in[11];
    const float* b2    = (const float*)d_in[12];
    const float* ln2_g = (const float*)d_in[13];
    const float* ln2_b = (const float*)d_in[14];
    const float* Wout  = (const float*)d_in[15];
    const float* bout  = (const float*)d_in[16];
    float* out = (float*)d_out;

    float* ws = (float*)d_ws;
    _Float16* qf16 = (_Float16*)ws;                         // [0, 0.5NX)
    _Float16* kf16 = (_Float16*)(ws + NX / 2);              // [0.5, 1NX)
    _Float16* vt16 = (_Float16*)(ws + NX);                  // [1, 1.5NX)
    float*    xb   = ws + 9 * NX / 2;                       // [4.5, 5.5NX)
    ushort*   xbf0 = (ushort*)(ws + 11 * NX / 2);           // [5.5, 6NX)
    ushort*   xbbf = (ushort*)(ws + 13 * NX / 2);           // [6.5, 7NX)
    ushort*   wbf  = (ushort*)(ws + 7 * NX);                // [7, ~7.26NX)
    float*    obuf = ws + 8 * NX;                           // [8, 9NX)

    MegaArgs margs;
    margs.x_in = x_in; margs.Wq = Wq; margs.bq = bq; margs.Wk = Wk; margs.bk = bk;
    margs.Wv = Wv; margs.bv = bv; margs.ln1_g = ln1_g; margs.ln1_b = ln1_b;
    margs.W1 = W1; margs.b1 = b1; margs.W2 = W2; margs.b2 = b2;
    margs.ln2_g = ln2_g; margs.ln2_b = ln2_b; margs.Wout = Wout; margs.bout = bout;
    margs.out = out; margs.wbf = wbf; margs.xbf0 = xbf0;
    margs.qf16 = qf16; margs.kf16 = kf16; margs.vt16 = vt16;
    margs.obuf = obuf; margs.xb = xb; margs.xbbf = xbbf;

    void* kargs[] = { &margs };
    hipError_t err = hipLaunchCooperativeKernel((const void*)mega_kernel,
                                                dim3(512), dim3(256), kargs, 0, stream);
    if (err != hipSuccess) {
        (void)hipGetLastError();   // clear error, take the proven 10-dispatch path
        const dim3 blk(256);
        prep_kernel_fb<<<dim3(10304), blk, 0, stream>>>(Wq, Wk, Wv, W1, W2, x_in, wbf, xbf0);
        const float* xcur = x_in;
        const ushort* xcur_bf = xbf0;
        for (int l = 0; l < Lq; ++l) {
            const ushort* wqt = wbf + (size_t)(0 * 3 + l) * 16384;
            const ushort* wkt = wbf + (size_t)(1 * 3 + l) * 16384;
            const ushort* wvt = wbf + (size_t)(2 * 3 + l) * 16384;
            const ushort* w1t = wbf + 147456 + (size_t)l * 65536;
            const ushort* w2t = wbf + 344064 + (size_t)l * 65536;

            qkv_kernel_fb<<<dim3(256, 3), blk, 0, stream>>>(
                xcur_bf, wqt, wkt, wvt, bq + l * Dq, bk + l * Dq, bv + l * Dq,
                qf16, kf16, vt16);
            attn_kernel_fb<<<dim3(Bq * Hq, 8), blk, 0, stream>>>(qf16, kf16, vt16, obuf);
            ffn_kernel_fb<<<dim3(512), blk, 0, stream>>>(
                obuf, xcur, ln1_g + l * Dq, ln1_b + l * Dq,
                w1t, b1 + l * DFFq, w2t, b2 + l * Dq,
                ln2_g + l * Dq, ln2_b + l * Dq,
                xb, xbbf, Wout, bout, out, (l == Lq - 1) ? 1 : 0);

            xcur = xb;
            xcur_bf = xbbf;
        }
    }
}

// Round 14
// 264.474 us; speedup vs baseline: 3.0810x; 3.0810x over previous
//
#include <hip/hip_runtime.h>
#include <math.h>

#define Bq 16
#define Sq 1024
#define Dq 128
#define Hq 8
#define DHq 16
#define DFFq 512
#define Lq 3
#define NCLS 6
#define NROWS (Bq * Sq)       // 16384
#define NX ((size_t)NROWS * Dq)   // 2,097,152 floats

typedef __attribute__((ext_vector_type(8))) short    bf16x8;
typedef __attribute__((ext_vector_type(4))) float    f32x4;
typedef __attribute__((ext_vector_type(4))) _Float16 f16x4;
typedef __attribute__((ext_vector_type(8))) _Float16 f16x8;

__device__ inline ushort f32_to_bf16(float f) {
    union { float f; unsigned u; } v; v.f = f;
    unsigned r = v.u + 0x7fffu + ((v.u >> 16) & 1u);
    return (ushort)(r >> 16);
}

// ---------------------------------------------------------------------------
// prep: cast+transpose weights to bf16 Wt[n][k]; cast x to bf16.
// Wq PRE-SCALED by 0.25 (ReLU commutes with positive scale).
// ---------------------------------------------------------------------------
__global__ __launch_bounds__(256) void prep_kernel(
    const float* __restrict__ Wqp, const float* __restrict__ Wkp,
    const float* __restrict__ Wvp, const float* __restrict__ W1p,
    const float* __restrict__ W2p, const float* __restrict__ xp,
    ushort* __restrict__ wbf, ushort* __restrict__ xbf)
{
    const int gid = blockIdx.x * 256 + threadIdx.x;
    if (gid < 147456) {                       // QKV transpose
        const int w   = gid / 49152;
        const int rem = gid - w * 49152;
        const int l   = rem >> 14;
        const int idx = rem & 16383;
        const int k   = idx >> 7;
        const int n   = idx & 127;
        const float* src = (w == 0) ? Wqp : (w == 1) ? Wkp : Wvp;
        const float scl = (w == 0) ? 0.25f : 1.0f;
        wbf[(size_t)(w * 3 + l) * 16384 + n * 128 + k] =
            f32_to_bf16(src[(size_t)l * 16384 + k * 128 + n] * scl);
    } else if (gid < 344064) {                // W1 [128][512]->[512][128]
        const int g   = gid - 147456;
        const int l   = g >> 16;
        const int idx = g & 65535;
        const int k   = idx >> 9;
        const int n   = idx & 511;
        wbf[147456 + (size_t)l * 65536 + n * 128 + k] =
            f32_to_bf16(W1p[(size_t)l * 65536 + k * 512 + n]);
    } else if (gid < 540672) {                // W2 [512][128]->[128][512]
        const int g   = gid - 344064;
        const int l   = g >> 16;
        const int idx = g & 65535;
        const int k   = idx >> 7;
        const int n   = idx & 127;
        wbf[344064 + (size_t)l * 65536 + n * 512 + k] =
            f32_to_bf16(W2p[(size_t)l * 65536 + k * 128 + n]);
    } else {                                  // x cast
        const int g = gid - 540672;
        xbf[g] = f32_to_bf16(xp[g]);
    }
}

// ---------------------------------------------------------------------------
// Standalone QKV GEMM (layer 0 only; R12-proven). grid (256, 3).
// y=0: Q (pre-scaled) -> [b,h,s,dh] f16  y=1: K -> [b,h,s,dh] f16
// y=2: V -> vt [b,h,dh,s] f16
// ---------------------------------------------------------------------------
__global__ __launch_bounds__(256) void gemm_qkv(
    const ushort* __restrict__ A,
    const ushort* __restrict__ wq, const ushort* __restrict__ wk,
    const ushort* __restrict__ wv,
    const float* __restrict__ bqp, const float* __restrict__ bkp,
    const float* __restrict__ bvp,
    _Float16* __restrict__ qo, _Float16* __restrict__ ko,
    _Float16* __restrict__ vo)
{
    __shared__ ushort As[64 * 40];
    __shared__ ushort Bs[128 * 40];

    const int sel  = blockIdx.y;
    const ushort* Bt   = (sel == 0) ? wq : (sel == 1) ? wk : wv;
    const float*  bias = (sel == 0) ? bqp : (sel == 1) ? bkp : bvp;
    const float   bscl = (sel == 0) ? 0.25f : 1.0f;

    const int tid  = threadIdx.x;
    const int row0 = blockIdx.x * 64;
    const int wave = tid >> 6;
    const int lane = tid & 63;
    const int quad = lane >> 4;
    const int m16  = lane & 15;
    const int wm   = wave >> 1;
    const int wn   = wave & 1;

    const int sar = tid >> 2;
    const int sac = (tid & 3) * 8;

    f32x4 acc[2][4];
    #pragma unroll
    for (int i = 0; i < 2; ++i)
        #pragma unroll
        for (int j = 0; j < 4; ++j) acc[i][j] = (f32x4)0.f;

    for (int k0 = 0; k0 < 128; k0 += 32) {
        bf16x8 av = *(const bf16x8*)(A + (size_t)(row0 + sar) * 128 + k0 + sac);
        const int r1 = tid >> 2, r2 = r1 + 64;
        bf16x8 bv1 = *(const bf16x8*)(Bt + (size_t)r1 * 128 + k0 + sac);
        bf16x8 bv2 = *(const bf16x8*)(Bt + (size_t)r2 * 128 + k0 + sac);

        __syncthreads();
        *(bf16x8*)&As[sar * 40 + sac] = av;
        *(bf16x8*)&Bs[r1 * 40 + sac]  = bv1;
        *(bf16x8*)&Bs[r2 * 40 + sac]  = bv2;
        __syncthreads();

        bf16x8 af[2], bf[4];
        #pragma unroll
        for (int i = 0; i < 2; ++i)
            af[i] = *(const bf16x8*)&As[(32 * wm + 16 * i + m16) * 40 + quad * 8];
        #pragma unroll
        for (int j = 0; j < 4; ++j)
            bf[j] = *(const bf16x8*)&Bs[(64 * wn + 16 * j + m16) * 40 + quad * 8];
        #pragma unroll
        for (int i = 0; i < 2; ++i)
            #pragma unroll
            for (int j = 0; j < 4; ++j)
                acc[i][j] = __builtin_amdgcn_mfma_f32_16x16x32_bf16(af[i], bf[j], acc[i][j], 0, 0, 0);
    }

    #pragma unroll
    for (int i = 0; i < 2; ++i) {
        #pragma unroll
        for (int j = 0; j < 4; ++j) {
            const int col = 64 * wn + 16 * j + m16;
            const float bb = bias[col] * bscl;
            const int hh = col >> 4, dh = col & 15;
            #pragma unroll
            for (int r = 0; r < 4; ++r) {
                float val = fmaxf(acc[i][j][r] + bb, 0.f);
                const int gr = row0 + 32 * wm + 16 * i + quad * 4 + r;
                const int b = gr >> 10, s = gr & 1023;
                if (sel == 2) {
                    vo[(((size_t)b * Hq + hh) * DHq + dh) * Sq + s] = (_Float16)val;
                } else {
                    _Float16* outp = (sel == 0) ? qo : ko;
                    outp[(((size_t)b * Hq + hh) * Sq + s) * DHq + dh] = (_Float16)val;
                }
            }
        }
    }
}

// ---------------------------------------------------------------------------
// FUSED FFN BLOCK (R12-proven: LN1 -> FFN1 -> FFN2 -> LN2) + NEXT-LAYER QKV
// in the epilogue (do_next=1): Phase D writes LN2 bf16 into the dead Af tile,
// then 3 GEMMs (A resident in LDS, W staged 64-K like Phase B/C) emit
// Q/K/V^T for layer l+1 — replaces the standalone qkv dispatch and the xbbf
// global round-trip. last=1: final projection instead.
// ---------------------------------------------------------------------------
__global__ __launch_bounds__(256) void gemm_ffn_fused(
    const float* __restrict__ o, const float* __restrict__ resid,
    const float* __restrict__ g1, const float* __restrict__ beta1,
    const ushort* __restrict__ W1t, const float* __restrict__ bias1,
    const ushort* __restrict__ W2t, const float* __restrict__ bias2,
    const float* __restrict__ g2, const float* __restrict__ beta2,
    float* __restrict__ xb,
    const ushort* __restrict__ wqn, const ushort* __restrict__ wkn,
    const ushort* __restrict__ wvn,
    const float* __restrict__ bqn, const float* __restrict__ bkn,
    const float* __restrict__ bvn,
    _Float16* __restrict__ qo, _Float16* __restrict__ ko,
    _Float16* __restrict__ vo, int do_next,
    const float* __restrict__ Wout, const float* __restrict__ bout,
    float* __restrict__ out, int last)
{
    __shared__ __align__(16) char smem[69120];
    ushort*    Af   = (ushort*)smem;                 // 32x136 bf16
    ushort*    Hs   = (ushort*)(smem + 8704);        // 32x520 bf16
    ushort*    Bs   = (ushort*)(smem + 41984);       // 128x72 staging
    float*     wo_s = (float*)(smem + 41984);        // overlays Bs in phase D(last)
    _Float16*  vals = (_Float16*)(smem + 60416);     // 32x132 f16
    float*     mus  = (float*)(smem + 68864);
    float*     rsds = (float*)(smem + 68992);

    const int tid  = threadIdx.x;
    const int row0 = blockIdx.x * 32;
    const int wave = tid >> 6;
    const int lane = tid & 63;
    const int quad = lane >> 4;
    const int m16  = lane & 15;
    const int wm   = wave >> 1;          // row half: 16*wm
    const int wn   = wave & 1;           // col half: 64*wn
    const int sac  = (tid & 3) * 8;
    const int r1   = tid >> 2, r2 = r1 + 64;

    // ---- Phase A: LN1, 8 rows/wave, each row once ----
    #pragma unroll 2
    for (int it = 0; it < 8; ++it) {
        const int rr = wave * 8 + it;
        const size_t base = (size_t)(row0 + rr) * Dq;
        float v0 = o[base + lane]      + resid[base + lane];
        float v1 = o[base + 64 + lane] + resid[base + 64 + lane];

        float s = v0 + v1;
        #pragma unroll
        for (int off = 32; off > 0; off >>= 1) s += __shfl_xor(s, off, 64);
        const float mu = s * (1.f / 128.f);
        const float d0 = v0 - mu, d1 = v1 - mu;
        float vs = d0 * d0 + d1 * d1;
        #pragma unroll
        for (int off = 32; off > 0; off >>= 1) vs += __shfl_xor(vs, off, 64);
        const float rstd = rsqrtf(vs * (1.f / 128.f) + 1e-8f);

        const float rv0 = g1[lane]      * d0 * rstd + beta1[lane];
        const float rv1 = g1[lane + 64] * d1 * rstd + beta1[lane + 64];
        Af[rr * 136 + lane]        = f32_to_bf16(rv0);
        Af[rr * 136 + 64 + lane]   = f32_to_bf16(rv1);
        vals[rr * 132 + lane]      = (_Float16)rv0;
        vals[rr * 132 + 64 + lane] = (_Float16)rv1;
    }

    // ---- Phase B: FFN1 (8 iters of 64-K), h -> Hs ----
    f32x4 acc[4];
    #pragma unroll
    for (int j = 0; j < 4; ++j) acc[j] = (f32x4)0.f;

    for (int idx = 0; idx < 8; ++idx) {
        const int cc = idx >> 1;
        const int k0 = (idx & 1) * 64;

        bf16x8 w11 = *(const bf16x8*)(W1t + (size_t)(cc * 128 + r1) * 128 + k0 + sac);
        bf16x8 w12 = *(const bf16x8*)(W1t + (size_t)(cc * 128 + r1) * 128 + k0 + 32 + sac);
        bf16x8 w21 = *(const bf16x8*)(W1t + (size_t)(cc * 128 + r2) * 128 + k0 + sac);
        bf16x8 w22 = *(const bf16x8*)(W1t + (size_t)(cc * 128 + r2) * 128 + k0 + 32 + sac);

        __syncthreads();   // idx==0: also guards Phase-A LDS writes
        *(bf16x8*)&Bs[r1 * 72 + sac]      = w11;
        *(bf16x8*)&Bs[r1 * 72 + 32 + sac] = w12;
        *(bf16x8*)&Bs[r2 * 72 + sac]      = w21;
        *(bf16x8*)&Bs[r2 * 72 + 32 + sac] = w22;
        __syncthreads();

        #pragma unroll
        for (int hh = 0; hh < 2; ++hh) {
            const int kk = k0 + hh * 32;
            const bf16x8 af = *(const bf16x8*)&Af[(16 * wm + m16) * 136 + kk + quad * 8];
            bf16x8 bf[4];
            #pragma unroll
            for (int j = 0; j < 4; ++j)
                bf[j] = *(const bf16x8*)&Bs[(64 * wn + 16 * j + m16) * 72 + hh * 32 + quad * 8];
            #pragma unroll
            for (int j = 0; j < 4; ++j)
                acc[j] = __builtin_amdgcn_mfma_f32_16x16x32_bf16(af, bf[j], acc[j], 0, 0, 0);
        }

        if (idx & 1) {
            #pragma unroll
            for (int j = 0; j < 4; ++j) {
                const int col = cc * 128 + 64 * wn + 16 * j + m16;
                const float bb = bias1[col];
                #pragma unroll
                for (int r = 0; r < 4; ++r) {
                    const int row = 16 * wm + quad * 4 + r;
                    Hs[row * 520 + col] = f32_to_bf16(fmaxf(acc[j][r] + bb, 0.f));
                }
                acc[j] = (f32x4)0.f;
            }
        }
    }

    // ---- Phase C: FFN2 (8 iters of 64-K) from resident Hs ----
    f32x4 acc2[4];
    #pragma unroll
    for (int j = 0; j < 4; ++j) acc2[j] = (f32x4)0.f;

    for (int kc = 0; kc < 8; ++kc) {
        const int k0 = kc * 64;

        bf16x8 w11 = *(const bf16x8*)(W2t + (size_t)r1 * DFFq + k0 + sac);
        bf16x8 w12 = *(const bf16x8*)(W2t + (size_t)r1 * DFFq + k0 + 32 + sac);
        bf16x8 w21 = *(const bf16x8*)(W2t + (size_t)r2 * DFFq + k0 + sac);
        bf16x8 w22 = *(const bf16x8*)(W2t + (size_t)r2 * DFFq + k0 + 32 + sac);

        __syncthreads();   // kc==0: also guards Phase-B Hs writes
        *(bf16x8*)&Bs[r1 * 72 + sac]      = w11;
        *(bf16x8*)&Bs[r1 * 72 + 32 + sac] = w12;
        *(bf16x8*)&Bs[r2 * 72 + sac]      = w21;
        *(bf16x8*)&Bs[r2 * 72 + 32 + sac] = w22;
        __syncthreads();

        #pragma unroll
        for (int hh = 0; hh < 2; ++hh) {
            const int kk = k0 + hh * 32;
            const bf16x8 af = *(const bf16x8*)&Hs[(16 * wm + m16) * 520 + kk + quad * 8];
            bf16x8 bf[4];
            #pragma unroll
            for (int j = 0; j < 4; ++j)
                bf[j] = *(const bf16x8*)&Bs[(64 * wn + 16 * j + m16) * 72 + hh * 32 + quad * 8];
            #pragma unroll
            for (int j = 0; j < 4; ++j)
                acc2[j] = __builtin_amdgcn_mfma_f32_16x16x32_bf16(af, bf[j], acc2[j], 0, 0, 0);
        }
    }

    // ---- Phase D: +bias +LN1-residual (vals), LN2 ----
    __syncthreads();

    float vreg[4][4];
    #pragma unroll
    for (int j = 0; j < 4; ++j) {
        const int col = 64 * wn + 16 * j + m16;
        const float bb = bias2[col];
        #pragma unroll
        for (int r = 0; r < 4; ++r) {
            const int row = 16 * wm + quad * 4 + r;
            float v = acc2[j][r] + bb + (float)vals[row * 132 + col];
            vreg[j][r] = v;
            vals[row * 132 + col] = (_Float16)v;
        }
    }
    if (last) {
        #pragma unroll
        for (int i = 0; i < 3; ++i) wo_s[tid + i * 256] = Wout[tid + i * 256];
    }
    __syncthreads();

    if (tid < 32) {
        float s = 0.f, s2 = 0.f;
        #pragma unroll 8
        for (int c = 0; c < Dq; ++c) {
            float x = (float)vals[tid * 132 + c];
            s += x; s2 = fmaf(x, x, s2);
        }
        const float mu  = s * (1.f / 128.f);
        const float var = s2 * (1.f / 128.f) - mu * mu;
        mus[tid]  = mu;
        rsds[tid] = rsqrtf(var + 1e-6f);
    }
    __syncthreads();

    if (!last) {
        // LN2 output: xb f32 (next-layer residual) + Af bf16 (A-operand for
        // the fused next-layer QKV below). Replaces the xbbf global buffer.
        #pragma unroll
        for (int j = 0; j < 4; ++j) {
            const int col = 64 * wn + 16 * j + m16;
            #pragma unroll
            for (int r = 0; r < 4; ++r) {
                const int row = 16 * wm + quad * 4 + r;
                const float rn = g2[col] * (vreg[j][r] - mus[row]) * rsds[row] + beta2[col];
                xb[(size_t)(row0 + row) * Dq + col] = rn;
                Af[row * 136 + col] = f32_to_bf16(rn);
            }
        }

        if (do_next) {
            // ---- next-layer QKV from resident Af (32 rows) ----
            for (int sel = 0; sel < 3; ++sel) {
                const ushort* Bt   = (sel == 0) ? wqn : (sel == 1) ? wkn : wvn;
                const float*  bias = (sel == 0) ? bqn : (sel == 1) ? bkn : bvn;
                const float   bscl = (sel == 0) ? 0.25f : 1.0f;

                f32x4 qacc[4];
                #pragma unroll
                for (int j = 0; j < 4; ++j) qacc[j] = (f32x4)0.f;

                for (int half = 0; half < 2; ++half) {
                    const int k0 = half * 64;
                    bf16x8 w11 = *(const bf16x8*)(Bt + (size_t)r1 * 128 + k0 + sac);
                    bf16x8 w12 = *(const bf16x8*)(Bt + (size_t)r1 * 128 + k0 + 32 + sac);
                    bf16x8 w21 = *(const bf16x8*)(Bt + (size_t)r2 * 128 + k0 + sac);
                    bf16x8 w22 = *(const bf16x8*)(Bt + (size_t)r2 * 128 + k0 + 32 + sac);

                    __syncthreads();   // first iter: guards Af writes above
                    *(bf16x8*)&Bs[r1 * 72 + sac]      = w11;
                    *(bf16x8*)&Bs[r1 * 72 + 32 + sac] = w12;
                    *(bf16x8*)&Bs[r2 * 72 + sac]      = w21;
                    *(bf16x8*)&Bs[r2 * 72 + 32 + sac] = w22;
                    __syncthreads();

                    #pragma unroll
                    for (int hh = 0; hh < 2; ++hh) {
                        const int kk = k0 + hh * 32;
                        const bf16x8 af = *(const bf16x8*)&Af[(16 * wm + m16) * 136 + kk + quad * 8];
                        bf16x8 bf[4];
                        #pragma unroll
                        for (int j = 0; j < 4; ++j)
                            bf[j] = *(const bf16x8*)&Bs[(64 * wn + 16 * j + m16) * 72 + hh * 32 + quad * 8];
                        #pragma unroll
                        for (int j = 0; j < 4; ++j)
                            qacc[j] = __builtin_amdgcn_mfma_f32_16x16x32_bf16(af, bf[j], qacc[j], 0, 0, 0);
                    }
                }

                #pragma unroll
                for (int j = 0; j < 4; ++j) {
                    const int col = 64 * wn + 16 * j + m16;
                    const float bb = bias[col] * bscl;
                    const int hh = col >> 4, dh = col & 15;
                    #pragma unroll
                    for (int r = 0; r < 4; ++r) {
                        float val = fmaxf(qacc[j][r] + bb, 0.f);
                        const int gr = row0 + 16 * wm + quad * 4 + r;
                        const int b = gr >> 10, s = gr & 1023;
                        if (sel == 2) {
                            vo[(((size_t)b * Hq + hh) * DHq + dh) * Sq + s] = (_Float16)val;
                        } else {
                            _Float16* outp = (sel == 0) ? qo : ko;
                            outp[(((size_t)b * Hq + hh) * Sq + s) * DHq + dh] = (_Float16)val;
                        }
                    }
                }
            }
        }
    } else {
        #pragma unroll
        for (int j = 0; j < 4; ++j) {
            const int col = 64 * wn + 16 * j + m16;
            #pragma unroll
            for (int r = 0; r < 4; ++r) {
                const int row = 16 * wm + quad * 4 + r;
                vals[row * 132 + col] =
                    (_Float16)(g2[col] * (vreg[j][r] - mus[row]) * rsds[row] + beta2[col]);
            }
        }
        __syncthreads();
        if (tid < 32 * NCLS) {
            const int row = tid / NCLS;
            const int c   = tid - row * NCLS;
            float a = bout[c];
            #pragma unroll 8
            for (int kk = 0; kk < Dq; ++kk)
                a = fmaf((float)vals[row * 132 + kk], wo_s[kk * NCLS + c], a);
            out[(size_t)(row0 + row) * NCLS + c] = a;
        }
    }
}

// ---------------------------------------------------------------------------
// f16 MFMA flash attention (R12-proven: qc=8, 2 Q-frags/wave).
// Q pre-scaled 0.25; no max-subtraction (validated R2..R13).
// ---------------------------------------------------------------------------
__global__ __launch_bounds__(256) void attn_mfma(
    const _Float16* __restrict__ q, const _Float16* __restrict__ k,
    const _Float16* __restrict__ vt, float* __restrict__ o)
{
    __shared__ _Float16 Ks[256 * 20];
    __shared__ _Float16 Vs[16 * 264];

    const int bh   = blockIdx.x;
    const int qc   = blockIdx.y;
    const int b    = bh >> 3;
    const int h    = bh & 7;
    const int tid  = threadIdx.x;
    const int wave = tid >> 6;
    const int lane = tid & 63;
    const int quad = lane >> 4;
    const int m16  = lane & 15;
    const int q0   = qc * 128 + wave * 32;

    const f16x4 qf0 = *(const f16x4*)(q + (((size_t)bh * Sq) + q0 + m16) * DHq + quad * 4);
    const f16x4 qf1 = *(const f16x4*)(q + (((size_t)bh * Sq) + q0 + 16 + m16) * DHq + quad * 4);

    const _Float16* kg  = k  + (size_t)bh * Sq * DHq;
    const _Float16* vtg = vt + (size_t)bh * DHq * Sq;

    f32x4 oacc0 = (f32x4)0.f, oacc1 = (f32x4)0.f;
    float lacc0 = 0.f, lacc1 = 0.f;

    const int krow = tid;
    const int vrow = tid >> 4;
    const int vcol = (tid & 15) * 16;

    for (int kb = 0; kb < 4; ++kb) {
        f16x8 ka  = *(const f16x8*)(kg + ((size_t)kb * 256 + krow) * DHq);
        f16x8 kb8 = *(const f16x8*)(kg + ((size_t)kb * 256 + krow) * DHq + 8);
        f16x8 va  = *(const f16x8*)(vtg + (size_t)vrow * Sq + kb * 256 + vcol);
        f16x8 vb  = *(const f16x8*)(vtg + (size_t)vrow * Sq + kb * 256 + vcol + 8);
        __syncthreads();
        *(f16x8*)&Ks[krow * 20 + 0] = ka;
        *(f16x8*)&Ks[krow * 20 + 8] = kb8;
        *(f16x8*)&Vs[vrow * 264 + vcol + 0] = va;
        *(f16x8*)&Vs[vrow * 264 + vcol + 8] = vb;
        __syncthreads();

        #pragma unroll 4
        for (int kt = 0; kt < 16; ++kt) {
            const f16x4 kf = *(const f16x4*)&Ks[(kt * 16 + m16) * 20 + quad * 4];
            const f16x4 vf = *(const f16x4*)&Vs[m16 * 264 + kt * 16 + quad * 4];

            f32x4 st0 = __builtin_amdgcn_mfma_f32_16x16x16f16(kf, qf0, (f32x4)0.f, 0, 0, 0);
            f32x4 st1 = __builtin_amdgcn_mfma_f32_16x16x16f16(kf, qf1, (f32x4)0.f, 0, 0, 0);

            float p00 = __expf(st0[0]);
            float p01 = __expf(st0[1]);
            float p02 = __expf(st0[2]);
            float p03 = __expf(st0[3]);
            float p10 = __expf(st1[0]);
            float p11 = __expf(st1[1]);
            float p12 = __expf(st1[2]);
            float p13 = __expf(st1[3]);
            lacc0 += (p00 + p01) + (p02 + p03);
            lacc1 += (p10 + p11) + (p12 + p13);

            f16x4 pf0, pf1;
            pf0[0] = (_Float16)p00; pf0[1] = (_Float16)p01;
            pf0[2] = (_Float16)p02; pf0[3] = (_Float16)p03;
            pf1[0] = (_Float16)p10; pf1[1] = (_Float16)p11;
            pf1[2] = (_Float16)p12; pf1[3] = (_Float16)p13;

            oacc0 = __builtin_amdgcn_mfma_f32_16x16x16f16(pf0, vf, oacc0, 0, 0, 0);
            oacc1 = __builtin_amdgcn_mfma_f32_16x16x16f16(pf1, vf, oacc1, 0, 0, 0);
        }
    }

    lacc0 += __shfl_xor(lacc0, 16, 64);
    lacc0 += __shfl_xor(lacc0, 32, 64);
    lacc1 += __shfl_xor(lacc1, 16, 64);
    lacc1 += __shfl_xor(lacc1, 32, 64);

    #pragma unroll
    for (int r = 0; r < 4; ++r) {
        const float ls0 = __shfl(lacc0, quad * 4 + r, 64);
        const float ls1 = __shfl(lacc1, quad * 4 + r, 64);
        o[((size_t)b * Sq + q0 + quad * 4 + r) * Dq + h * DHq + m16]      = oacc0[r] / ls0;
        o[((size_t)b * Sq + q0 + 16 + quad * 4 + r) * Dq + h * DHq + m16] = oacc1[r] / ls1;
    }
}

// ---------------------------------------------------------------------------
extern "C" void kernel_launch(void* const* d_in, const int* in_sizes, int n_in,
                              void* d_out, int out_size, void* d_ws, size_t ws_size,
                              hipStream_t stream)
{
    const float* x_in  = (const float*)d_in[0];
    const float* Wq    = (const float*)d_in[1];
    const float* bq    = (const float*)d_in[2];
    const float* Wk    = (const float*)d_in[3];
    const float* bk    = (const float*)d_in[4];
    const float* Wv    = (const float*)d_in[5];
    const float* bv    = (const float*)d_in[6];
    const float* ln1_g = (const float*)d_in[7];
    const float* ln1_b = (const float*)d_in[8];
    const float* W1    = (const float*)d_in[9];
    const float* b1    = (const float*)d_in[10];
    const float* W2    = (const float*)d_in[11];
    const float* b2    = (const float*)d_in[12];
    const float* ln2_g = (const float*)d_in[13];
    const float* ln2_b = (const float*)d_in[14];
    const float* Wout  = (const float*)d_in[15];
    const float* bout  = (const float*)d_in[16];
    float* out = (float*)d_out;

    float* ws = (float*)d_ws;
    _Float16* qf16 = (_Float16*)ws;                         // [0, 0.5NX)
    _Float16* kf16 = (_Float16*)(ws + NX / 2);              // [0.5, 1NX)
    _Float16* vt16 = (_Float16*)(ws + NX);                  // [1, 1.5NX)
    float*    xb   = ws + 9 * NX / 2;                       // [4.5, 5.5NX)
    ushort*   xbf0 = (ushort*)(ws + 11 * NX / 2);           // [5.5, 6NX)
    ushort*   wbf  = (ushort*)(ws + 7 * NX);                // [7, ~7.26NX)
    float*    obuf = ws + 8 * NX;                           // [8, 9NX)

    prep_kernel<<<dim3(10304), dim3(256), 0, stream>>>(Wq, Wk, Wv, W1, W2, x_in, wbf, xbf0);

    const dim3 blk(256);

    // layer-0 QKV (from x cast)
    {
        const ushort* wqt = wbf + (size_t)0 * 16384;
        const ushort* wkt = wbf + (size_t)3 * 16384;
        const ushort* wvt = wbf + (size_t)6 * 16384;
        gemm_qkv<<<dim3(256, 3), blk, 0, stream>>>(
            xbf0, wqt, wkt, wvt, bq, bk, bv, qf16, kf16, vt16);
    }

    const float* xcur = x_in;
    for (int l = 0; l < Lq; ++l) {
        const ushort* w1t = wbf + 147456 + (size_t)l * 65536;
        const ushort* w2t = wbf + 344064 + (size_t)l * 65536;
        const int next = (l < Lq - 1) ? 1 : 0;
        const int ln   = l + 1;
        const ushort* wqn = next ? (wbf + (size_t)(0 * 3 + ln) * 16384) : wbf;
        const ushort* wkn = next ? (wbf + (size_t)(1 * 3 + ln) * 16384) : wbf;
        const ushort* wvn = next ? (wbf + (size_t)(2 * 3 + ln) * 16384) : wbf;
        const float*  bqn = next ? (bq + ln * Dq) : bq;
        const float*  bkn = next ? (bk + ln * Dq) : bk;
        const float*  bvn = next ? (bv + ln * Dq) : bv;

        attn_mfma<<<dim3(Bq * Hq, 8), blk, 0, stream>>>(qf16, kf16, vt16, obuf);

        gemm_ffn_fused<<<dim3(512), blk, 0, stream>>>(
            obuf, xcur, ln1_g + l * Dq, ln1_b + l * Dq,
            w1t, b1 + l * DFFq, w2t, b2 + l * Dq,
            ln2_g + l * Dq, ln2_b + l * Dq,
            xb,
            wqn, wkn, wvn, bqn, bkn, bvn,
            qf16, kf16, vt16, next,
            Wout, bout, out, (l == Lq - 1) ? 1 : 0);

        xcur = xb;
    }
}

// Round 15
// 253.450 us; speedup vs baseline: 3.2150x; 1.0435x over previous
//
#include <hip/hip_runtime.h>
#include <math.h>

#define Bq 16
#define Sq 1024
#define Dq 128
#define Hq 8
#define DHq 16
#define DFFq 512
#define Lq 3
#define NCLS 6
#define NROWS (Bq * Sq)       // 16384
#define NX ((size_t)NROWS * Dq)   // 2,097,152 floats

// Q pre-scale: (1/sqrt(DH)) * log2(e), so softmax probs = 2^score (raw v_exp)
#define QSCL 0.36067376022224085f

typedef __attribute__((ext_vector_type(8))) short    bf16x8;
typedef __attribute__((ext_vector_type(4))) float    f32x4;
typedef __attribute__((ext_vector_type(4))) _Float16 f16x4;
typedef __attribute__((ext_vector_type(8))) _Float16 f16x8;

__device__ inline ushort f32_to_bf16(float f) {
    union { float f; unsigned u; } v; v.f = f;
    unsigned r = v.u + 0x7fffu + ((v.u >> 16) & 1u);
    return (ushort)(r >> 16);
}

// raw 2^x via v_exp_f32 (ISA-guaranteed); avoids __expf's extra v_mul
__device__ __forceinline__ float exp2_raw(float x) {
    float r;
    asm("v_exp_f32 %0, %1" : "=v"(r) : "v"(x));
    return r;
}

// ---------------------------------------------------------------------------
// prep: cast+transpose weights to bf16 Wt[n][k]; cast x to bf16.
// Wq PRE-SCALED by QSCL (ReLU commutes with positive scale).
// ---------------------------------------------------------------------------
__global__ __launch_bounds__(256) void prep_kernel(
    const float* __restrict__ Wqp, const float* __restrict__ Wkp,
    const float* __restrict__ Wvp, const float* __restrict__ W1p,
    const float* __restrict__ W2p, const float* __restrict__ xp,
    ushort* __restrict__ wbf, ushort* __restrict__ xbf)
{
    const int gid = blockIdx.x * 256 + threadIdx.x;
    if (gid < 147456) {                       // QKV transpose
        const int w   = gid / 49152;
        const int rem = gid - w * 49152;
        const int l   = rem >> 14;
        const int idx = rem & 16383;
        const int k   = idx >> 7;
        const int n   = idx & 127;
        const float* src = (w == 0) ? Wqp : (w == 1) ? Wkp : Wvp;
        const float scl = (w == 0) ? QSCL : 1.0f;
        wbf[(size_t)(w * 3 + l) * 16384 + n * 128 + k] =
            f32_to_bf16(src[(size_t)l * 16384 + k * 128 + n] * scl);
    } else if (gid < 344064) {                // W1 [128][512]->[512][128]
        const int g   = gid - 147456;
        const int l   = g >> 16;
        const int idx = g & 65535;
        const int k   = idx >> 9;
        const int n   = idx & 511;
        wbf[147456 + (size_t)l * 65536 + n * 128 + k] =
            f32_to_bf16(W1p[(size_t)l * 65536 + k * 512 + n]);
    } else if (gid < 540672) {                // W2 [512][128]->[128][512]
        const int g   = gid - 344064;
        const int l   = g >> 16;
        const int idx = g & 65535;
        const int k   = idx >> 7;
        const int n   = idx & 127;
        wbf[344064 + (size_t)l * 65536 + n * 512 + k] =
            f32_to_bf16(W2p[(size_t)l * 65536 + k * 128 + n]);
    } else {                                  // x cast
        const int g = gid - 540672;
        xbf[g] = f32_to_bf16(xp[g]);
    }
}

// ---------------------------------------------------------------------------
// Standalone QKV GEMM (layer 0 only; R12-proven). grid (256, 3).
// y=0: Q (pre-scaled QSCL) -> [b,h,s,dh] f16  y=1: K -> [b,h,s,dh] f16
// y=2: V -> vt [b,h,dh,s] f16
// ---------------------------------------------------------------------------
__global__ __launch_bounds__(256) void gemm_qkv(
    const ushort* __restrict__ A,
    const ushort* __restrict__ wq, const ushort* __restrict__ wk,
    const ushort* __restrict__ wv,
    const float* __restrict__ bqp, const float* __restrict__ bkp,
    const float* __restrict__ bvp,
    _Float16* __restrict__ qo, _Float16* __restrict__ ko,
    _Float16* __restrict__ vo)
{
    __shared__ ushort As[64 * 40];
    __shared__ ushort Bs[128 * 40];

    const int sel  = blockIdx.y;
    const ushort* Bt   = (sel == 0) ? wq : (sel == 1) ? wk : wv;
    const float*  bias = (sel == 0) ? bqp : (sel == 1) ? bkp : bvp;
    const float   bscl = (sel == 0) ? QSCL : 1.0f;

    const int tid  = threadIdx.x;
    const int row0 = blockIdx.x * 64;
    const int wave = tid >> 6;
    const int lane = tid & 63;
    const int quad = lane >> 4;
    const int m16  = lane & 15;
    const int wm   = wave >> 1;
    const int wn   = wave & 1;

    const int sar = tid >> 2;
    const int sac = (tid & 3) * 8;

    f32x4 acc[2][4];
    #pragma unroll
    for (int i = 0; i < 2; ++i)
        #pragma unroll
        for (int j = 0; j < 4; ++j) acc[i][j] = (f32x4)0.f;

    for (int k0 = 0; k0 < 128; k0 += 32) {
        bf16x8 av = *(const bf16x8*)(A + (size_t)(row0 + sar) * 128 + k0 + sac);
        const int r1 = tid >> 2, r2 = r1 + 64;
        bf16x8 bv1 = *(const bf16x8*)(Bt + (size_t)r1 * 128 + k0 + sac);
        bf16x8 bv2 = *(const bf16x8*)(Bt + (size_t)r2 * 128 + k0 + sac);

        __syncthreads();
        *(bf16x8*)&As[sar * 40 + sac] = av;
        *(bf16x8*)&Bs[r1 * 40 + sac]  = bv1;
        *(bf16x8*)&Bs[r2 * 40 + sac]  = bv2;
        __syncthreads();

        bf16x8 af[2], bf[4];
        #pragma unroll
        for (int i = 0; i < 2; ++i)
            af[i] = *(const bf16x8*)&As[(32 * wm + 16 * i + m16) * 40 + quad * 8];
        #pragma unroll
        for (int j = 0; j < 4; ++j)
            bf[j] = *(const bf16x8*)&Bs[(64 * wn + 16 * j + m16) * 40 + quad * 8];
        #pragma unroll
        for (int i = 0; i < 2; ++i)
            #pragma unroll
            for (int j = 0; j < 4; ++j)
                acc[i][j] = __builtin_amdgcn_mfma_f32_16x16x32_bf16(af[i], bf[j], acc[i][j], 0, 0, 0);
    }

    #pragma unroll
    for (int i = 0; i < 2; ++i) {
        #pragma unroll
        for (int j = 0; j < 4; ++j) {
            const int col = 64 * wn + 16 * j + m16;
            const float bb = bias[col] * bscl;
            const int hh = col >> 4, dh = col & 15;
            #pragma unroll
            for (int r = 0; r < 4; ++r) {
                float val = fmaxf(acc[i][j][r] + bb, 0.f);
                const int gr = row0 + 32 * wm + 16 * i + quad * 4 + r;
                const int b = gr >> 10, s = gr & 1023;
                if (sel == 2) {
                    vo[(((size_t)b * Hq + hh) * DHq + dh) * Sq + s] = (_Float16)val;
                } else {
                    _Float16* outp = (sel == 0) ? qo : ko;
                    outp[(((size_t)b * Hq + hh) * Sq + s) * DHq + dh] = (_Float16)val;
                }
            }
        }
    }
}

// ---------------------------------------------------------------------------
// FUSED FFN BLOCK (R14-proven: LN1 -> FFN1 -> FFN2 -> LN2 + next-layer QKV
// in the epilogue). o (attention output) now arrives as f16.
// ---------------------------------------------------------------------------
__global__ __launch_bounds__(256) void gemm_ffn_fused(
    const _Float16* __restrict__ o, const float* __restrict__ resid,
    const float* __restrict__ g1, const float* __restrict__ beta1,
    const ushort* __restrict__ W1t, const float* __restrict__ bias1,
    const ushort* __restrict__ W2t, const float* __restrict__ bias2,
    const float* __restrict__ g2, const float* __restrict__ beta2,
    float* __restrict__ xb,
    const ushort* __restrict__ wqn, const ushort* __restrict__ wkn,
    const ushort* __restrict__ wvn,
    const float* __restrict__ bqn, const float* __restrict__ bkn,
    const float* __restrict__ bvn,
    _Float16* __restrict__ qo, _Float16* __restrict__ ko,
    _Float16* __restrict__ vo, int do_next,
    const float* __restrict__ Wout, const float* __restrict__ bout,
    float* __restrict__ out, int last)
{
    __shared__ __align__(16) char smem[69120];
    ushort*    Af   = (ushort*)smem;                 // 32x136 bf16
    ushort*    Hs   = (ushort*)(smem + 8704);        // 32x520 bf16
    ushort*    Bs   = (ushort*)(smem + 41984);       // 128x72 staging
    float*     wo_s = (float*)(smem + 41984);        // overlays Bs in phase D(last)
    _Float16*  vals = (_Float16*)(smem + 60416);     // 32x132 f16
    float*     mus  = (float*)(smem + 68864);
    float*     rsds = (float*)(smem + 68992);

    const int tid  = threadIdx.x;
    const int row0 = blockIdx.x * 32;
    const int wave = tid >> 6;
    const int lane = tid & 63;
    const int quad = lane >> 4;
    const int m16  = lane & 15;
    const int wm   = wave >> 1;          // row half: 16*wm
    const int wn   = wave & 1;           // col half: 64*wn
    const int sac  = (tid & 3) * 8;
    const int r1   = tid >> 2, r2 = r1 + 64;

    // ---- Phase A: LN1, 8 rows/wave, each row once ----
    #pragma unroll 2
    for (int it = 0; it < 8; ++it) {
        const int rr = wave * 8 + it;
        const size_t base = (size_t)(row0 + rr) * Dq;
        float v0 = (float)o[base + lane]      + resid[base + lane];
        float v1 = (float)o[base + 64 + lane] + resid[base + 64 + lane];

        float s = v0 + v1;
        #pragma unroll
        for (int off = 32; off > 0; off >>= 1) s += __shfl_xor(s, off, 64);
        const float mu = s * (1.f / 128.f);
        const float d0 = v0 - mu, d1 = v1 - mu;
        float vs = d0 * d0 + d1 * d1;
        #pragma unroll
        for (int off = 32; off > 0; off >>= 1) vs += __shfl_xor(vs, off, 64);
        const float rstd = rsqrtf(vs * (1.f / 128.f) + 1e-8f);

        const float rv0 = g1[lane]      * d0 * rstd + beta1[lane];
        const float rv1 = g1[lane + 64] * d1 * rstd + beta1[lane + 64];
        Af[rr * 136 + lane]        = f32_to_bf16(rv0);
        Af[rr * 136 + 64 + lane]   = f32_to_bf16(rv1);
        vals[rr * 132 + lane]      = (_Float16)rv0;
        vals[rr * 132 + 64 + lane] = (_Float16)rv1;
    }

    // ---- Phase B: FFN1 (8 iters of 64-K), h -> Hs ----
    f32x4 acc[4];
    #pragma unroll
    for (int j = 0; j < 4; ++j) acc[j] = (f32x4)0.f;

    for (int idx = 0; idx < 8; ++idx) {
        const int cc = idx >> 1;
        const int k0 = (idx & 1) * 64;

        bf16x8 w11 = *(const bf16x8*)(W1t + (size_t)(cc * 128 + r1) * 128 + k0 + sac);
        bf16x8 w12 = *(const bf16x8*)(W1t + (size_t)(cc * 128 + r1) * 128 + k0 + 32 + sac);
        bf16x8 w21 = *(const bf16x8*)(W1t + (size_t)(cc * 128 + r2) * 128 + k0 + sac);
        bf16x8 w22 = *(const bf16x8*)(W1t + (size_t)(cc * 128 + r2) * 128 + k0 + 32 + sac);

        __syncthreads();   // idx==0: also guards Phase-A LDS writes
        *(bf16x8*)&Bs[r1 * 72 + sac]      = w11;
        *(bf16x8*)&Bs[r1 * 72 + 32 + sac] = w12;
        *(bf16x8*)&Bs[r2 * 72 + sac]      = w21;
        *(bf16x8*)&Bs[r2 * 72 + 32 + sac] = w22;
        __syncthreads();

        #pragma unroll
        for (int hh = 0; hh < 2; ++hh) {
            const int kk = k0 + hh * 32;
            const bf16x8 af = *(const bf16x8*)&Af[(16 * wm + m16) * 136 + kk + quad * 8];
            bf16x8 bf[4];
            #pragma unroll
            for (int j = 0; j < 4; ++j)
                bf[j] = *(const bf16x8*)&Bs[(64 * wn + 16 * j + m16) * 72 + hh * 32 + quad * 8];
            #pragma unroll
            for (int j = 0; j < 4; ++j)
                acc[j] = __builtin_amdgcn_mfma_f32_16x16x32_bf16(af, bf[j], acc[j], 0, 0, 0);
        }

        if (idx & 1) {
            #pragma unroll
            for (int j = 0; j < 4; ++j) {
                const int col = cc * 128 + 64 * wn + 16 * j + m16;
                const float bb = bias1[col];
                #pragma unroll
                for (int r = 0; r < 4; ++r) {
                    const int row = 16 * wm + quad * 4 + r;
                    Hs[row * 520 + col] = f32_to_bf16(fmaxf(acc[j][r] + bb, 0.f));
                }
                acc[j] = (f32x4)0.f;
            }
        }
    }

    // ---- Phase C: FFN2 (8 iters of 64-K) from resident Hs ----
    f32x4 acc2[4];
    #pragma unroll
    for (int j = 0; j < 4; ++j) acc2[j] = (f32x4)0.f;

    for (int kc = 0; kc < 8; ++kc) {
        const int k0 = kc * 64;

        bf16x8 w11 = *(const bf16x8*)(W2t + (size_t)r1 * DFFq + k0 + sac);
        bf16x8 w12 = *(const bf16x8*)(W2t + (size_t)r1 * DFFq + k0 + 32 + sac);
        bf16x8 w21 = *(const bf16x8*)(W2t + (size_t)r2 * DFFq + k0 + sac);
        bf16x8 w22 = *(const bf16x8*)(W2t + (size_t)r2 * DFFq + k0 + 32 + sac);

        __syncthreads();   // kc==0: also guards Phase-B Hs writes
        *(bf16x8*)&Bs[r1 * 72 + sac]      = w11;
        *(bf16x8*)&Bs[r1 * 72 + 32 + sac] = w12;
        *(bf16x8*)&Bs[r2 * 72 + sac]      = w21;
        *(bf16x8*)&Bs[r2 * 72 + 32 + sac] = w22;
        __syncthreads();

        #pragma unroll
        for (int hh = 0; hh < 2; ++hh) {
            const int kk = k0 + hh * 32;
            const bf16x8 af = *(const bf16x8*)&Hs[(16 * wm + m16) * 520 + kk + quad * 8];
            bf16x8 bf[4];
            #pragma unroll
            for (int j = 0; j < 4; ++j)
                bf[j] = *(const bf16x8*)&Bs[(64 * wn + 16 * j + m16) * 72 + hh * 32 + quad * 8];
            #pragma unroll
            for (int j = 0; j < 4; ++j)
                acc2[j] = __builtin_amdgcn_mfma_f32_16x16x32_bf16(af, bf[j], acc2[j], 0, 0, 0);
        }
    }

    // ---- Phase D: +bias +LN1-residual (vals), LN2 ----
    __syncthreads();

    float vreg[4][4];
    #pragma unroll
    for (int j = 0; j < 4; ++j) {
        const int col = 64 * wn + 16 * j + m16;
        const float bb = bias2[col];
        #pragma unroll
        for (int r = 0; r < 4; ++r) {
            const int row = 16 * wm + quad * 4 + r;
            float v = acc2[j][r] + bb + (float)vals[row * 132 + col];
            vreg[j][r] = v;
            vals[row * 132 + col] = (_Float16)v;
        }
    }
    if (last) {
        #pragma unroll
        for (int i = 0; i < 3; ++i) wo_s[tid + i * 256] = Wout[tid + i * 256];
    }
    __syncthreads();

    if (tid < 32) {
        float s = 0.f, s2 = 0.f;
        #pragma unroll 8
        for (int c = 0; c < Dq; ++c) {
            float x = (float)vals[tid * 132 + c];
            s += x; s2 = fmaf(x, x, s2);
        }
        const float mu  = s * (1.f / 128.f);
        const float var = s2 * (1.f / 128.f) - mu * mu;
        mus[tid]  = mu;
        rsds[tid] = rsqrtf(var + 1e-6f);
    }
    __syncthreads();

    if (!last) {
        // LN2 output: xb f32 (next-layer residual) + Af bf16 (A-operand for
        // the fused next-layer QKV below).
        #pragma unroll
        for (int j = 0; j < 4; ++j) {
            const int col = 64 * wn + 16 * j + m16;
            #pragma unroll
            for (int r = 0; r < 4; ++r) {
                const int row = 16 * wm + quad * 4 + r;
                const float rn = g2[col] * (vreg[j][r] - mus[row]) * rsds[row] + beta2[col];
                xb[(size_t)(row0 + row) * Dq + col] = rn;
                Af[row * 136 + col] = f32_to_bf16(rn);
            }
        }

        if (do_next) {
            // ---- next-layer QKV from resident Af (32 rows) ----
            for (int sel = 0; sel < 3; ++sel) {
                const ushort* Bt   = (sel == 0) ? wqn : (sel == 1) ? wkn : wvn;
                const float*  bias = (sel == 0) ? bqn : (sel == 1) ? bkn : bvn;
                const float   bscl = (sel == 0) ? QSCL : 1.0f;

                f32x4 qacc[4];
                #pragma unroll
                for (int j = 0; j < 4; ++j) qacc[j] = (f32x4)0.f;

                for (int half = 0; half < 2; ++half) {
                    const int k0 = half * 64;
                    bf16x8 w11 = *(const bf16x8*)(Bt + (size_t)r1 * 128 + k0 + sac);
                    bf16x8 w12 = *(const bf16x8*)(Bt + (size_t)r1 * 128 + k0 + 32 + sac);
                    bf16x8 w21 = *(const bf16x8*)(Bt + (size_t)r2 * 128 + k0 + sac);
                    bf16x8 w22 = *(const bf16x8*)(Bt + (size_t)r2 * 128 + k0 + 32 + sac);

                    __syncthreads();   // first iter: guards Af writes above
                    *(bf16x8*)&Bs[r1 * 72 + sac]      = w11;
                    *(bf16x8*)&Bs[r1 * 72 + 32 + sac] = w12;
                    *(bf16x8*)&Bs[r2 * 72 + sac]      = w21;
                    *(bf16x8*)&Bs[r2 * 72 + 32 + sac] = w22;
                    __syncthreads();

                    #pragma unroll
                    for (int hh = 0; hh < 2; ++hh) {
                        const int kk = k0 + hh * 32;
                        const bf16x8 af = *(const bf16x8*)&Af[(16 * wm + m16) * 136 + kk + quad * 8];
                        bf16x8 bf[4];
                        #pragma unroll
                        for (int j = 0; j < 4; ++j)
                            bf[j] = *(const bf16x8*)&Bs[(64 * wn + 16 * j + m16) * 72 + hh * 32 + quad * 8];
                        #pragma unroll
                        for (int j = 0; j < 4; ++j)
                            qacc[j] = __builtin_amdgcn_mfma_f32_16x16x32_bf16(af, bf[j], qacc[j], 0, 0, 0);
                    }
                }

                #pragma unroll
                for (int j = 0; j < 4; ++j) {
                    const int col = 64 * wn + 16 * j + m16;
                    const float bb = bias[col] * bscl;
                    const int hh = col >> 4, dh = col & 15;
                    #pragma unroll
                    for (int r = 0; r < 4; ++r) {
                        float val = fmaxf(qacc[j][r] + bb, 0.f);
                        const int gr = row0 + 16 * wm + quad * 4 + r;
                        const int b = gr >> 10, s = gr & 1023;
                        if (sel == 2) {
                            vo[(((size_t)b * Hq + hh) * DHq + dh) * Sq + s] = (_Float16)val;
                        } else {
                            _Float16* outp = (sel == 0) ? qo : ko;
                            outp[(((size_t)b * Hq + hh) * Sq + s) * DHq + dh] = (_Float16)val;
                        }
                    }
                }
            }
        }
    } else {
        #pragma unroll
        for (int j = 0; j < 4; ++j) {
            const int col = 64 * wn + 16 * j + m16;
            #pragma unroll
            for (int r = 0; r < 4; ++r) {
                const int row = 16 * wm + quad * 4 + r;
                vals[row * 132 + col] =
                    (_Float16)(g2[col] * (vreg[j][r] - mus[row]) * rsds[row] + beta2[col]);
            }
        }
        __syncthreads();
        if (tid < 32 * NCLS) {
            const int row = tid / NCLS;
            const int c   = tid - row * NCLS;
            float a = bout[c];
            #pragma unroll 8
            for (int kk = 0; kk < Dq; ++kk)
                a = fmaf((float)vals[row * 132 + kk], wo_s[kk * NCLS + c], a);
            out[(size_t)(row0 + row) * NCLS + c] = a;
        }
    }
}

// ---------------------------------------------------------------------------
// f16 MFMA flash attention (R12-proven structure: qc=8, 2 Q-frags/wave).
// Q pre-scaled by QSCL so p = 2^score via raw v_exp_f32 (no per-score mul).
// Output o now written as f16. No max-subtraction (validated R2..R14).
// ---------------------------------------------------------------------------
__global__ __launch_bounds__(256) void attn_mfma(
    const _Float16* __restrict__ q, const _Float16* __restrict__ k,
    const _Float16* __restrict__ vt, _Float16* __restrict__ o)
{
    __shared__ _Float16 Ks[256 * 20];
    __shared__ _Float16 Vs[16 * 264];

    const int bh   = blockIdx.x;
    const int qc   = blockIdx.y;
    const int b    = bh >> 3;
    const int h    = bh & 7;
    const int tid  = threadIdx.x;
    const int wave = tid >> 6;
    const int lane = tid & 63;
    const int quad = lane >> 4;
    const int m16  = lane & 15;
    const int q0   = qc * 128 + wave * 32;

    const f16x4 qf0 = *(const f16x4*)(q + (((size_t)bh * Sq) + q0 + m16) * DHq + quad * 4);
    const f16x4 qf1 = *(const f16x4*)(q + (((size_t)bh * Sq) + q0 + 16 + m16) * DHq + quad * 4);

    const _Float16* kg  = k  + (size_t)bh * Sq * DHq;
    const _Float16* vtg = vt + (size_t)bh * DHq * Sq;

    f32x4 oacc0 = (f32x4)0.f, oacc1 = (f32x4)0.f;
    float lacc0 = 0.f, lacc1 = 0.f;

    const int krow = tid;
    const int vrow = tid >> 4;
    const int vcol = (tid & 15) * 16;

    for (int kb = 0; kb < 4; ++kb) {
        f16x8 ka  = *(const f16x8*)(kg + ((size_t)kb * 256 + krow) * DHq);
        f16x8 kb8 = *(const f16x8*)(kg + ((size_t)kb * 256 + krow) * DHq + 8);
        f16x8 va  = *(const f16x8*)(vtg + (size_t)vrow * Sq + kb * 256 + vcol);
        f16x8 vb  = *(const f16x8*)(vtg + (size_t)vrow * Sq + kb * 256 + vcol + 8);
        __syncthreads();
        *(f16x8*)&Ks[krow * 20 + 0] = ka;
        *(f16x8*)&Ks[krow * 20 + 8] = kb8;
        *(f16x8*)&Vs[vrow * 264 + vcol + 0] = va;
        *(f16x8*)&Vs[vrow * 264 + vcol + 8] = vb;
        __syncthreads();

        #pragma unroll 4
        for (int kt = 0; kt < 16; ++kt) {
            const f16x4 kf = *(const f16x4*)&Ks[(kt * 16 + m16) * 20 + quad * 4];
            const f16x4 vf = *(const f16x4*)&Vs[m16 * 264 + kt * 16 + quad * 4];

            f32x4 st0 = __builtin_amdgcn_mfma_f32_16x16x16f16(kf, qf0, (f32x4)0.f, 0, 0, 0);
            f32x4 st1 = __builtin_amdgcn_mfma_f32_16x16x16f16(kf, qf1, (f32x4)0.f, 0, 0, 0);

            float p00 = exp2_raw(st0[0]);
            float p01 = exp2_raw(st0[1]);
            float p02 = exp2_raw(st0[2]);
            float p03 = exp2_raw(st0[3]);
            float p10 = exp2_raw(st1[0]);
            float p11 = exp2_raw(st1[1]);
            float p12 = exp2_raw(st1[2]);
            float p13 = exp2_raw(st1[3]);
            lacc0 += (p00 + p01) + (p02 + p03);
            lacc1 += (p10 + p11) + (p12 + p13);

            f16x4 pf0, pf1;
            pf0[0] = (_Float16)p00; pf0[1] = (_Float16)p01;
            pf0[2] = (_Float16)p02; pf0[3] = (_Float16)p03;
            pf1[0] = (_Float16)p10; pf1[1] = (_Float16)p11;
            pf1[2] = (_Float16)p12; pf1[3] = (_Float16)p13;

            oacc0 = __builtin_amdgcn_mfma_f32_16x16x16f16(pf0, vf, oacc0, 0, 0, 0);
            oacc1 = __builtin_amdgcn_mfma_f32_16x16x16f16(pf1, vf, oacc1, 0, 0, 0);
        }
    }

    lacc0 += __shfl_xor(lacc0, 16, 64);
    lacc0 += __shfl_xor(lacc0, 32, 64);
    lacc1 += __shfl_xor(lacc1, 16, 64);
    lacc1 += __shfl_xor(lacc1, 32, 64);

    #pragma unroll
    for (int r = 0; r < 4; ++r) {
        const float ls0 = __shfl(lacc0, quad * 4 + r, 64);
        const float ls1 = __shfl(lacc1, quad * 4 + r, 64);
        o[((size_t)b * Sq + q0 + quad * 4 + r) * Dq + h * DHq + m16]      = (_Float16)(oacc0[r] / ls0);
        o[((size_t)b * Sq + q0 + 16 + quad * 4 + r) * Dq + h * DHq + m16] = (_Float16)(oacc1[r] / ls1);
    }
}

// ---------------------------------------------------------------------------
extern "C" void kernel_launch(void* const* d_in, const int* in_sizes, int n_in,
                              void* d_out, int out_size, void* d_ws, size_t ws_size,
                              hipStream_t stream)
{
    const float* x_in  = (const float*)d_in[0];
    const float* Wq    = (const float*)d_in[1];
    const float* bq    = (const float*)d_in[2];
    const float* Wk    = (const float*)d_in[3];
    const float* bk    = (const float*)d_in[4];
    const float* Wv    = (const float*)d_in[5];
    const float* bv    = (const float*)d_in[6];
    const float* ln1_g = (const float*)d_in[7];
    const float* ln1_b = (const float*)d_in[8];
    const float* W1    = (const float*)d_in[9];
    const float* b1    = (const float*)d_in[10];
    const float* W2    = (const float*)d_in[11];
    const float* b2    = (const float*)d_in[12];
    const float* ln2_g = (const float*)d_in[13];
    const float* ln2_b = (const float*)d_in[14];
    const float* Wout  = (const float*)d_in[15];
    const float* bout  = (const float*)d_in[16];
    float* out = (float*)d_out;

    float* ws = (float*)d_ws;
    _Float16* qf16 = (_Float16*)ws;                         // [0, 0.5NX)
    _Float16* kf16 = (_Float16*)(ws + NX / 2);              // [0.5, 1NX)
    _Float16* vt16 = (_Float16*)(ws + NX);                  // [1, 1.5NX)
    float*    xb   = ws + 9 * NX / 2;                       // [4.5, 5.5NX)
    ushort*   xbf0 = (ushort*)(ws + 11 * NX / 2);           // [5.5, 6NX)
    ushort*   wbf  = (ushort*)(ws + 7 * NX);                // [7, ~7.26NX)
    _Float16* obuf = (_Float16*)(ws + 8 * NX);              // [8, 8.25NX) f16

    prep_kernel<<<dim3(10304), dim3(256), 0, stream>>>(Wq, Wk, Wv, W1, W2, x_in, wbf, xbf0);

    const dim3 blk(256);

    // layer-0 QKV (from x cast)
    {
        const ushort* wqt = wbf + (size_t)0 * 16384;
        const ushort* wkt = wbf + (size_t)3 * 16384;
        const ushort* wvt = wbf + (size_t)6 * 16384;
        gemm_qkv<<<dim3(256, 3), blk, 0, stream>>>(
            xbf0, wqt, wkt, wvt, bq, bk, bv, qf16, kf16, vt16);
    }

    const float* xcur = x_in;
    for (int l = 0; l < Lq; ++l) {
        const ushort* w1t = wbf + 147456 + (size_t)l * 65536;
        const ushort* w2t = wbf + 344064 + (size_t)l * 65536;
        const int next = (l < Lq - 1) ? 1 : 0;
        const int ln   = l + 1;
        const ushort* wqn = next ? (wbf + (size_t)(0 * 3 + ln) * 16384) : wbf;
        const ushort* wkn = next ? (wbf + (size_t)(1 * 3 + ln) * 16384) : wbf;
        const ushort* wvn = next ? (wbf + (size_t)(2 * 3 + ln) * 16384) : wbf;
        const float*  bqn = next ? (bq + ln * Dq) : bq;
        const float*  bkn = next ? (bk + ln * Dq) : bk;
        const float*  bvn = next ? (bv + ln * Dq) : bv;

        attn_mfma<<<dim3(Bq * Hq, 8), blk, 0, stream>>>(qf16, kf16, vt16, obuf);

        gemm_ffn_fused<<<dim3(512), blk, 0, stream>>>(
            obuf, xcur, ln1_g + l * Dq, ln1_b + l * Dq,
            w1t, b1 + l * DFFq, w2t, b2 + l * Dq,
            ln2_g + l * Dq, ln2_b + l * Dq,
            xb,
            wqn, wkn, wvn, bqn, bkn, bvn,
            qf16, kf16, vt16, next,
            Wout, bout, out, (l == Lq - 1) ? 1 : 0);

        xcur = xb;
    }
}